// Round 1
// baseline (1013.556 us; speedup 1.0000x reference)
//
#include <hip/hip_runtime.h>
#include <cstdint>
#include <cstddef>

#define E_HID 256
#define R_HID 128
#define NREL  1000
#define EPSF  1e-16f

// ---- ordered-float encoding for atomicMax on signed floats ----
__device__ __forceinline__ unsigned encf(float f) {
  unsigned u = __float_as_uint(f);
  return (u & 0x80000000u) ? ~u : (u | 0x80000000u);
}
__device__ __forceinline__ float decf(unsigned u) {
  unsigned b = (u & 0x80000000u) ? (u ^ 0x80000000u) : ~u;
  return __uint_as_float(b);
}

// ================= K1: x_r_h = x_e@W_h, x_r_t = x_e@W_t, fused s-scores ====
// Block: 256 threads = 16(tx: col groups) x 16(ty: node groups)
// Tile: 64 nodes x 256 cols (cols 0..127 -> W_h, 128..255 -> W_t)
// Thread: 4 nodes x 16 cols; cols are 4 float4 chunks at c = 64*j + 4*tx
__global__ __launch_bounds__(256) void k1_gemm(
    const float* __restrict__ xe,
    const float* __restrict__ Wh, const float* __restrict__ Wt,
    const float* __restrict__ ah1, const float* __restrict__ ah2,
    const float* __restrict__ at1, const float* __restrict__ at2,
    float* __restrict__ xh, float* __restrict__ xt,
    float* __restrict__ sh1, float* __restrict__ sh2,
    float* __restrict__ st1, float* __restrict__ st2, int N)
{
  __shared__ float xT[32][68];    // transposed x tile, stride 68 = conflict-free
  __shared__ float Wc[32][256];   // concat W tile
  const int tid = threadIdx.x;
  const int tx = tid & 15, ty = tid >> 4;
  const int n0 = blockIdx.x * 64;

  float4 acc[4][4];
  #pragma unroll
  for (int n = 0; n < 4; ++n)
    #pragma unroll
    for (int j = 0; j < 4; ++j) acc[n][j] = make_float4(0.f, 0.f, 0.f, 0.f);

  for (int kt = 0; kt < 8; ++kt) {
    const int k0 = kt * 32;
    { // stage x tile (transposed). coalesced float4 reads along k.
      const int n  = tid >> 2;         // 0..63
      const int kk0 = (tid & 3) * 8;   // 0,8,16,24
      float4 v0 = make_float4(0,0,0,0), v1 = make_float4(0,0,0,0);
      if (n0 + n < N) {
        const float* src = xe + (size_t)(n0 + n) * E_HID + k0 + kk0;
        v0 = *(const float4*)(src);
        v1 = *(const float4*)(src + 4);
      }
      xT[kk0+0][n] = v0.x; xT[kk0+1][n] = v0.y; xT[kk0+2][n] = v0.z; xT[kk0+3][n] = v0.w;
      xT[kk0+4][n] = v1.x; xT[kk0+5][n] = v1.y; xT[kk0+6][n] = v1.z; xT[kk0+7][n] = v1.w;
    }
    // stage W tile, coalesced
    #pragma unroll
    for (int r2 = 0; r2 < 8; ++r2) {
      const int kk = r2 * 4 + (tid >> 6);
      const int c4 = (tid & 63) * 4;
      float4 wv;
      if (c4 < 128) wv = *(const float4*)(Wh + (size_t)(k0 + kk) * R_HID + c4);
      else          wv = *(const float4*)(Wt + (size_t)(k0 + kk) * R_HID + (c4 - 128));
      *(float4*)&Wc[kk][c4] = wv;
    }
    __syncthreads();
    #pragma unroll 8
    for (int kk = 0; kk < 32; ++kk) {
      const float4 xv = *(const float4*)&xT[kk][ty * 4];
      float4 wv[4];
      wv[0] = *(const float4*)&Wc[kk][      4 * tx];
      wv[1] = *(const float4*)&Wc[kk][ 64 + 4 * tx];
      wv[2] = *(const float4*)&Wc[kk][128 + 4 * tx];
      wv[3] = *(const float4*)&Wc[kk][192 + 4 * tx];
      const float xn[4] = {xv.x, xv.y, xv.z, xv.w};
      #pragma unroll
      for (int n = 0; n < 4; ++n)
        #pragma unroll
        for (int j = 0; j < 4; ++j) {
          acc[n][j].x += xn[n] * wv[j].x;
          acc[n][j].y += xn[n] * wv[j].y;
          acc[n][j].z += xn[n] * wv[j].z;
          acc[n][j].w += xn[n] * wv[j].w;
        }
    }
    __syncthreads();
  }
  // epilogue: write x_r tiles + fused per-node score dots
  float4 vh1[2], vh2[2], vt1[2], vt2[2];
  #pragma unroll
  for (int j = 0; j < 2; ++j) {
    vh1[j] = *(const float4*)(ah1 + 64 * j + 4 * tx);
    vt1[j] = *(const float4*)(at1 + 64 * j + 4 * tx);
    vh2[j] = *(const float4*)(ah2 + 64 * j + 4 * tx);
    vt2[j] = *(const float4*)(at2 + 64 * j + 4 * tx);
  }
  #pragma unroll
  for (int n = 0; n < 4; ++n) {
    const int node = n0 + ty * 4 + n;
    const bool ok = node < N;
    float ph1 = 0.f, ph2 = 0.f, pt1 = 0.f, pt2 = 0.f;
    if (ok) {
      *(float4*)(xh + (size_t)node * R_HID +      4 * tx) = acc[n][0];
      *(float4*)(xh + (size_t)node * R_HID + 64 + 4 * tx) = acc[n][1];
      *(float4*)(xt + (size_t)node * R_HID +      4 * tx) = acc[n][2];
      *(float4*)(xt + (size_t)node * R_HID + 64 + 4 * tx) = acc[n][3];
      #pragma unroll
      for (int j = 0; j < 2; ++j) {
        ph1 += acc[n][j].x*vh1[j].x + acc[n][j].y*vh1[j].y + acc[n][j].z*vh1[j].z + acc[n][j].w*vh1[j].w;
        pt1 += acc[n][j].x*vt1[j].x + acc[n][j].y*vt1[j].y + acc[n][j].z*vt1[j].z + acc[n][j].w*vt1[j].w;
        ph2 += acc[n][j+2].x*vh2[j].x + acc[n][j+2].y*vh2[j].y + acc[n][j+2].z*vh2[j].z + acc[n][j+2].w*vh2[j].w;
        pt2 += acc[n][j+2].x*vt2[j].x + acc[n][j+2].y*vt2[j].y + acc[n][j+2].z*vt2[j].z + acc[n][j+2].w*vt2[j].w;
      }
    }
    #pragma unroll
    for (int ofs = 1; ofs < 16; ofs <<= 1) {
      ph1 += __shfl_xor(ph1, ofs, 16);
      ph2 += __shfl_xor(ph2, ofs, 16);
      pt1 += __shfl_xor(pt1, ofs, 16);
      pt2 += __shfl_xor(pt2, ofs, 16);
    }
    if (ok && tx == 0) { sh1[node] = ph1; sh2[node] = ph2; st1[node] = pt1; st2[node] = pt2; }
  }
}

// ================= K2: per-edge scores -> segment max (atomicMax) + histogram
__global__ __launch_bounds__(256) void k2_edge(
    const int* __restrict__ ei, const int* __restrict__ rel,
    const float* __restrict__ sh1, const float* __restrict__ sh2,
    const float* __restrict__ st1, const float* __restrict__ st2,
    unsigned* __restrict__ m1u, unsigned* __restrict__ m2u,
    unsigned* __restrict__ cnt, int E)
{
  int i = blockIdx.x * 256 + threadIdx.x;
  if (i >= E) return;
  int h = ei[i], t = ei[E + i], r = rel[i];
  float e1 = sh1[h] + sh2[t];
  float e2 = st1[h] + st2[t];
  float l1 = e1 >= 0.f ? e1 : 0.01f * e1;
  float l2 = e2 >= 0.f ? e2 : 0.01f * e2;
  atomicMax(m1u + r, encf(l1));
  atomicMax(m2u + r, encf(l2));
  atomicAdd(cnt + r, 1u);
}

// ================= K3: exclusive prefix sum over cnt + decode maxes =========
__global__ __launch_bounds__(1024) void k3_scan(
    const unsigned* __restrict__ cnt, unsigned* __restrict__ offs,
    const unsigned* __restrict__ m1u, const unsigned* __restrict__ m2u,
    float* __restrict__ m1f, float* __restrict__ m2f)
{
  __shared__ unsigned s[1024];
  const int t = threadIdx.x;
  s[t] = (t < NREL) ? cnt[t] : 0u;
  __syncthreads();
  for (int ofs = 1; ofs < 1024; ofs <<= 1) {
    unsigned add = (t >= ofs) ? s[t - ofs] : 0u;
    __syncthreads();
    s[t] += add;
    __syncthreads();
  }
  if (t == 0) offs[0] = 0u;
  if (t < NREL) {
    offs[t + 1] = s[t];
    m1f[t] = decf(m1u[t]);
    m2f[t] = decf(m2u[t]);
  }
}

// ================= K4: counting-sort scatter, w = exp(l - m) ================
__global__ __launch_bounds__(256) void k4_scatter(
    const int* __restrict__ ei, const int* __restrict__ rel,
    const float* __restrict__ sh1, const float* __restrict__ sh2,
    const float* __restrict__ st1, const float* __restrict__ st2,
    const float* __restrict__ m1f, const float* __restrict__ m2f,
    const unsigned* __restrict__ offs, unsigned* __restrict__ cur,
    int* __restrict__ hs, int* __restrict__ ts,
    float* __restrict__ w1s, float* __restrict__ w2s, int E)
{
  int i = blockIdx.x * 256 + threadIdx.x;
  if (i >= E) return;
  int h = ei[i], t = ei[E + i], r = rel[i];
  float e1 = sh1[h] + sh2[t];
  float e2 = st1[h] + st2[t];
  float l1 = e1 >= 0.f ? e1 : 0.01f * e1;
  float l2 = e2 >= 0.f ? e2 : 0.01f * e2;
  float w1 = expf(l1 - m1f[r]);
  float w2 = expf(l2 - m2f[r]);
  unsigned p = offs[r] + atomicAdd(cur + r, 1u);
  hs[p] = h; ts[p] = t; w1s[p] = w1; w2s[p] = w2;
}

// ================= K5: per-relation weighted gather-reduce ==================
// grid = NREL*4; block = 256 = 4 wave-teams; each wave: 1 edge row / iter,
// lane covers dims {2*lane, 2*lane+1} (512B coalesced row read).
#define SPLIT 4
__global__ __launch_bounds__(256) void k5_reduce(
    const unsigned* __restrict__ offs,
    const int* __restrict__ hs, const int* __restrict__ ts,
    const float* __restrict__ w1s, const float* __restrict__ w2s,
    const float* __restrict__ xh, const float* __restrict__ xt,
    float* __restrict__ accH, float* __restrict__ accT,
    float* __restrict__ S1, float* __restrict__ S2)
{
  const int r    = blockIdx.x >> 2;
  const int sp   = blockIdx.x & 3;
  const int team = threadIdx.x >> 6;
  const int lane = threadIdx.x & 63;
  const unsigned start = offs[r], end = offs[r + 1];
  const unsigned len = end - start;
  const int ci = sp * 4 + team;  // 0..15
  unsigned b0 = start + (unsigned)(((unsigned long long)len * ci) >> 4);
  unsigned b1 = start + (unsigned)(((unsigned long long)len * (ci + 1)) >> 4);
  const int d0 = lane * 2;

  float a1x = 0.f, a1y = 0.f, a2x = 0.f, a2y = 0.f, sw1 = 0.f, sw2 = 0.f;
  unsigned p = b0;
  for (; p + 4 <= b1; p += 4) {
    int   h_[4], t_[4];
    float u_[4], v_[4];
    #pragma unroll
    for (int u = 0; u < 4; ++u) {
      h_[u] = hs[p + u]; t_[u] = ts[p + u];
      u_[u] = w1s[p + u]; v_[u] = w2s[p + u];
    }
    #pragma unroll
    for (int u = 0; u < 4; ++u) {
      float2 xa = *(const float2*)(xh + (size_t)h_[u] * R_HID + d0);
      float2 xb = *(const float2*)(xt + (size_t)t_[u] * R_HID + d0);
      a1x += u_[u] * xa.x; a1y += u_[u] * xa.y;
      a2x += v_[u] * xb.x; a2y += v_[u] * xb.y;
      sw1 += u_[u]; sw2 += v_[u];
    }
  }
  for (; p < b1; ++p) {
    int h = hs[p], t = ts[p];
    float w1 = w1s[p], w2 = w2s[p];
    float2 xa = *(const float2*)(xh + (size_t)h * R_HID + d0);
    float2 xb = *(const float2*)(xt + (size_t)t * R_HID + d0);
    a1x += w1 * xa.x; a1y += w1 * xa.y;
    a2x += w2 * xb.x; a2y += w2 * xb.y;
    sw1 += w1; sw2 += w2;
  }
  atomicAdd(accH + (size_t)r * R_HID + d0,     a1x);
  atomicAdd(accH + (size_t)r * R_HID + d0 + 1, a1y);
  atomicAdd(accT + (size_t)r * R_HID + d0,     a2x);
  atomicAdd(accT + (size_t)r * R_HID + d0 + 1, a2y);
  if (lane == 0) { atomicAdd(S1 + r, sw1); atomicAdd(S2 + r, sw2); }
}

// ================= K6: finalize out = accH/(S1+eps) + accT/(S2+eps) =========
__global__ __launch_bounds__(256) void k6_final(
    const float* __restrict__ accH, const float* __restrict__ accT,
    const float* __restrict__ S1, const float* __restrict__ S2,
    float* __restrict__ out)
{
  int i = blockIdx.x * 256 + threadIdx.x;
  if (i >= NREL * R_HID) return;
  int r = i >> 7;
  out[i] = accH[i] / (S1[r] + EPSF) + accT[i] / (S2[r] + EPSF);
}

extern "C" void kernel_launch(void* const* d_in, const int* in_sizes, int n_in,
                              void* d_out, int out_size, void* d_ws, size_t ws_size,
                              hipStream_t stream) {
  const float* xe  = (const float*)d_in[0];
  const int*   ei  = (const int*)d_in[1];
  const int*   rel = (const int*)d_in[2];
  const float* Wh  = (const float*)d_in[3];
  const float* Wt  = (const float*)d_in[4];
  const float* ah1 = (const float*)d_in[5];
  const float* ah2 = (const float*)d_in[6];
  const float* at1 = (const float*)d_in[7];
  const float* at2 = (const float*)d_in[8];
  const int N = in_sizes[0] / E_HID;
  const int E = in_sizes[2];

  char* w = (char*)d_ws;
  size_t o = 0;
  auto alloc = [&](size_t bytes) -> void* {
    void* p = w + o;
    o = (o + bytes + 255) & ~(size_t)255;
    return p;
  };
  float* xh  = (float*)alloc((size_t)N * R_HID * 4);
  float* xt  = (float*)alloc((size_t)N * R_HID * 4);
  float* sh1 = (float*)alloc((size_t)N * 4);
  float* sh2 = (float*)alloc((size_t)N * 4);
  float* st1 = (float*)alloc((size_t)N * 4);
  float* st2 = (float*)alloc((size_t)N * 4);
  int*   hs  = (int*)alloc((size_t)E * 4);
  int*   ts  = (int*)alloc((size_t)E * 4);
  float* w1s = (float*)alloc((size_t)E * 4);
  float* w2s = (float*)alloc((size_t)E * 4);
  const size_t zstart = o;  // everything below must start zeroed
  unsigned* m1u  = (unsigned*)alloc((size_t)NREL * 4);
  unsigned* m2u  = (unsigned*)alloc((size_t)NREL * 4);
  unsigned* cnt  = (unsigned*)alloc((size_t)NREL * 4);
  unsigned* cur  = (unsigned*)alloc((size_t)NREL * 4);
  unsigned* offs = (unsigned*)alloc((size_t)(NREL + 1) * 4);
  float* m1f = (float*)alloc((size_t)NREL * 4);
  float* m2f = (float*)alloc((size_t)NREL * 4);
  float* S1  = (float*)alloc((size_t)NREL * 4);
  float* S2  = (float*)alloc((size_t)NREL * 4);
  float* accH = (float*)alloc((size_t)NREL * R_HID * 4);
  float* accT = (float*)alloc((size_t)NREL * R_HID * 4);
  const size_t zbytes = o - zstart;

  hipMemsetAsync(w + zstart, 0, zbytes, stream);

  k1_gemm<<<(N + 63) / 64, 256, 0, stream>>>(xe, Wh, Wt, ah1, ah2, at1, at2,
                                             xh, xt, sh1, sh2, st1, st2, N);
  k2_edge<<<(E + 255) / 256, 256, 0, stream>>>(ei, rel, sh1, sh2, st1, st2,
                                               m1u, m2u, cnt, E);
  k3_scan<<<1, 1024, 0, stream>>>(cnt, offs, m1u, m2u, m1f, m2f);
  k4_scatter<<<(E + 255) / 256, 256, 0, stream>>>(ei, rel, sh1, sh2, st1, st2,
                                                  m1f, m2f, offs, cur,
                                                  hs, ts, w1s, w2s, E);
  k5_reduce<<<NREL * SPLIT, 256, 0, stream>>>(offs, hs, ts, w1s, w2s, xh, xt,
                                              accH, accT, S1, S2);
  k6_final<<<(NREL * R_HID + 255) / 256, 256, 0, stream>>>(accH, accT, S1, S2,
                                                           (float*)d_out);
}

// Round 2
// 321.998 us; speedup vs baseline: 3.1477x; 3.1477x over previous
//
#include <hip/hip_runtime.h>
#include <hip/hip_fp16.h>
#include <cstdint>
#include <cstddef>

#define E_HID 256
#define R_HID 128
#define NREL  1000
#define EPSF  1e-16f
#define NB    512   // grid-stride blocks for edge passes (k2/k4)

// ---- ordered-float encoding for atomicMax on signed floats ----
__device__ __forceinline__ unsigned encf(float f) {
  unsigned u = __float_as_uint(f);
  return (u & 0x80000000u) ? ~u : (u | 0x80000000u);
}
__device__ __forceinline__ float decf(unsigned u) {
  unsigned b = (u & 0x80000000u) ? (u ^ 0x80000000u) : ~u;
  return __uint_as_float(b);
}

struct h4s { __half2 a, b; };
__device__ __forceinline__ h4s packf4(float4 v) {
  h4s r; r.a = __floats2half2_rn(v.x, v.y); r.b = __floats2half2_rn(v.z, v.w); return r;
}

// ================= K1: x_r_h = x_e@W_h, x_r_t = x_e@W_t (fp16 out), fused s-scores
// Block: 256 threads = 16(tx) x 16(ty); tile 64 nodes x 256 cols (128 Wh | 128 Wt)
__global__ __launch_bounds__(256) void k1_gemm(
    const float* __restrict__ xe,
    const float* __restrict__ Wh, const float* __restrict__ Wt,
    const float* __restrict__ ah1, const float* __restrict__ ah2,
    const float* __restrict__ at1, const float* __restrict__ at2,
    __half* __restrict__ xhH, __half* __restrict__ xtH,
    float* __restrict__ sh1, float* __restrict__ sh2,
    float* __restrict__ st1, float* __restrict__ st2, int N)
{
  __shared__ float xT[32][68];    // 16B-aligned stride (68*4=272? 272%16==0)
  __shared__ float Wc[32][256];
  const int tid = threadIdx.x;
  const int tx = tid & 15, ty = tid >> 4;
  const int n0 = blockIdx.x * 64;

  float4 acc[4][4];
  #pragma unroll
  for (int n = 0; n < 4; ++n)
    #pragma unroll
    for (int j = 0; j < 4; ++j) acc[n][j] = make_float4(0.f, 0.f, 0.f, 0.f);

  for (int kt = 0; kt < 8; ++kt) {
    const int k0 = kt * 32;
    { // stage x tile (transposed)
      const int n  = tid >> 2;
      const int kk0 = (tid & 3) * 8;
      float4 v0 = make_float4(0,0,0,0), v1 = make_float4(0,0,0,0);
      if (n0 + n < N) {
        const float* src = xe + (size_t)(n0 + n) * E_HID + k0 + kk0;
        v0 = *(const float4*)(src);
        v1 = *(const float4*)(src + 4);
      }
      xT[kk0+0][n] = v0.x; xT[kk0+1][n] = v0.y; xT[kk0+2][n] = v0.z; xT[kk0+3][n] = v0.w;
      xT[kk0+4][n] = v1.x; xT[kk0+5][n] = v1.y; xT[kk0+6][n] = v1.z; xT[kk0+7][n] = v1.w;
    }
    #pragma unroll
    for (int r2 = 0; r2 < 8; ++r2) {
      const int kk = r2 * 4 + (tid >> 6);
      const int c4 = (tid & 63) * 4;
      float4 wv;
      if (c4 < 128) wv = *(const float4*)(Wh + (size_t)(k0 + kk) * R_HID + c4);
      else          wv = *(const float4*)(Wt + (size_t)(k0 + kk) * R_HID + (c4 - 128));
      *(float4*)&Wc[kk][c4] = wv;
    }
    __syncthreads();
    #pragma unroll 8
    for (int kk = 0; kk < 32; ++kk) {
      const float4 xv = *(const float4*)&xT[kk][ty * 4];
      float4 wv[4];
      wv[0] = *(const float4*)&Wc[kk][      4 * tx];
      wv[1] = *(const float4*)&Wc[kk][ 64 + 4 * tx];
      wv[2] = *(const float4*)&Wc[kk][128 + 4 * tx];
      wv[3] = *(const float4*)&Wc[kk][192 + 4 * tx];
      const float xn[4] = {xv.x, xv.y, xv.z, xv.w};
      #pragma unroll
      for (int n = 0; n < 4; ++n)
        #pragma unroll
        for (int j = 0; j < 4; ++j) {
          acc[n][j].x += xn[n] * wv[j].x;
          acc[n][j].y += xn[n] * wv[j].y;
          acc[n][j].z += xn[n] * wv[j].z;
          acc[n][j].w += xn[n] * wv[j].w;
        }
    }
    __syncthreads();
  }
  float4 vh1[2], vh2[2], vt1[2], vt2[2];
  #pragma unroll
  for (int j = 0; j < 2; ++j) {
    vh1[j] = *(const float4*)(ah1 + 64 * j + 4 * tx);
    vt1[j] = *(const float4*)(at1 + 64 * j + 4 * tx);
    vh2[j] = *(const float4*)(ah2 + 64 * j + 4 * tx);
    vt2[j] = *(const float4*)(at2 + 64 * j + 4 * tx);
  }
  #pragma unroll
  for (int n = 0; n < 4; ++n) {
    const int node = n0 + ty * 4 + n;
    const bool ok = node < N;
    float ph1 = 0.f, ph2 = 0.f, pt1 = 0.f, pt2 = 0.f;
    if (ok) {
      *(h4s*)(xhH + (size_t)node * R_HID +      4 * tx) = packf4(acc[n][0]);
      *(h4s*)(xhH + (size_t)node * R_HID + 64 + 4 * tx) = packf4(acc[n][1]);
      *(h4s*)(xtH + (size_t)node * R_HID +      4 * tx) = packf4(acc[n][2]);
      *(h4s*)(xtH + (size_t)node * R_HID + 64 + 4 * tx) = packf4(acc[n][3]);
      #pragma unroll
      for (int j = 0; j < 2; ++j) {
        ph1 += acc[n][j].x*vh1[j].x + acc[n][j].y*vh1[j].y + acc[n][j].z*vh1[j].z + acc[n][j].w*vh1[j].w;
        pt1 += acc[n][j].x*vt1[j].x + acc[n][j].y*vt1[j].y + acc[n][j].z*vt1[j].z + acc[n][j].w*vt1[j].w;
        ph2 += acc[n][j+2].x*vh2[j].x + acc[n][j+2].y*vh2[j].y + acc[n][j+2].z*vh2[j].z + acc[n][j+2].w*vh2[j].w;
        pt2 += acc[n][j+2].x*vt2[j].x + acc[n][j+2].y*vt2[j].y + acc[n][j+2].z*vt2[j].z + acc[n][j+2].w*vt2[j].w;
      }
    }
    #pragma unroll
    for (int ofs = 1; ofs < 16; ofs <<= 1) {
      ph1 += __shfl_xor(ph1, ofs, 16);
      ph2 += __shfl_xor(ph2, ofs, 16);
      pt1 += __shfl_xor(pt1, ofs, 16);
      pt2 += __shfl_xor(pt2, ofs, 16);
    }
    if (ok && tx == 0) { sh1[node] = ph1; sh2[node] = ph2; st1[node] = pt1; st2[node] = pt2; }
  }
}

// ================= K2: per-edge scores -> LDS-hierarchical segment max + per-block histogram
__global__ __launch_bounds__(256) void k2_edge(
    const int* __restrict__ ei, const int* __restrict__ rel,
    const float* __restrict__ sh1, const float* __restrict__ sh2,
    const float* __restrict__ st1, const float* __restrict__ st2,
    float* __restrict__ le1, float* __restrict__ le2,
    unsigned* __restrict__ m1u, unsigned* __restrict__ m2u,
    unsigned* __restrict__ blockCnt, int E)
{
  __shared__ unsigned lcnt[NREL];
  __shared__ unsigned lm1[NREL];
  __shared__ unsigned lm2[NREL];
  const int tid = threadIdx.x;
  const unsigned NEG = encf(-1e30f);
  for (int j = tid; j < NREL; j += 256) { lcnt[j] = 0u; lm1[j] = NEG; lm2[j] = NEG; }
  __syncthreads();
  for (int i = blockIdx.x * 256 + tid; i < E; i += NB * 256) {
    int h = ei[i], t = ei[E + i], r = rel[i];
    float e1 = sh1[h] + sh2[t];
    float e2 = st1[h] + st2[t];
    float l1 = e1 >= 0.f ? e1 : 0.01f * e1;
    float l2 = e2 >= 0.f ? e2 : 0.01f * e2;
    le1[i] = l1; le2[i] = l2;
    atomicMax(&lm1[r], encf(l1));
    atomicMax(&lm2[r], encf(l2));
    atomicAdd(&lcnt[r], 1u);
  }
  __syncthreads();
  for (int j = tid; j < NREL; j += 256) {
    blockCnt[(size_t)blockIdx.x * NREL + j] = lcnt[j];
    if (lm1[j] != NEG) atomicMax(m1u + j, lm1[j]);
    if (lm2[j] != NEG) atomicMax(m2u + j, lm2[j]);
  }
}

// ================= K3a: per-relation exclusive scan over block counts ========
__global__ __launch_bounds__(64) void k3a_scan(
    const unsigned* __restrict__ blockCnt, unsigned* __restrict__ pre,
    unsigned* __restrict__ cnt)
{
  const int r = blockIdx.x;
  const int lane = threadIdx.x;
  unsigned running = 0u;
  for (int b0 = 0; b0 < NB; b0 += 64) {
    const int b = b0 + lane;
    unsigned v = (b < NB) ? blockCnt[(size_t)b * NREL + r] : 0u;
    unsigned inc = v;
    #pragma unroll
    for (int ofs = 1; ofs < 64; ofs <<= 1) {
      unsigned n = __shfl_up(inc, ofs, 64);
      if (lane >= ofs) inc += n;
    }
    if (b < NB) pre[(size_t)b * NREL + r] = running + inc - v;
    running += __shfl(inc, 63, 64);
  }
  if (lane == 0) cnt[r] = running;
}

// ================= K3b: scan totals -> offs; decode maxes ===================
__global__ __launch_bounds__(1024) void k3b_scan(
    const unsigned* __restrict__ cnt, unsigned* __restrict__ offs,
    const unsigned* __restrict__ m1u, const unsigned* __restrict__ m2u,
    float* __restrict__ m1f, float* __restrict__ m2f)
{
  __shared__ unsigned s[1024];
  const int t = threadIdx.x;
  s[t] = (t < NREL) ? cnt[t] : 0u;
  __syncthreads();
  for (int ofs = 1; ofs < 1024; ofs <<= 1) {
    unsigned add = (t >= ofs) ? s[t - ofs] : 0u;
    __syncthreads();
    s[t] += add;
    __syncthreads();
  }
  if (t == 0) offs[0] = 0u;
  if (t < NREL) {
    offs[t + 1] = s[t];
    m1f[t] = decf(m1u[t]);
    m2f[t] = decf(m2u[t]);
  }
}

// ================= K4: counting-sort scatter (no global atomics) ============
__global__ __launch_bounds__(256) void k4_scatter(
    const int* __restrict__ ei, const int* __restrict__ rel,
    const float* __restrict__ le1, const float* __restrict__ le2,
    const float* __restrict__ m1f, const float* __restrict__ m2f,
    const unsigned* __restrict__ offs, const unsigned* __restrict__ pre,
    float4* __restrict__ meta, int E)
{
  __shared__ unsigned lcur[NREL];
  __shared__ unsigned lbase[NREL];
  __shared__ float lm1[NREL];
  __shared__ float lm2[NREL];
  const int tid = threadIdx.x;
  for (int j = tid; j < NREL; j += 256) {
    lcur[j] = 0u;
    lbase[j] = offs[j] + pre[(size_t)blockIdx.x * NREL + j];
    lm1[j] = m1f[j];
    lm2[j] = m2f[j];
  }
  __syncthreads();
  for (int i = blockIdx.x * 256 + tid; i < E; i += NB * 256) {
    int h = ei[i], t = ei[E + i], r = rel[i];
    float w1 = expf(le1[i] - lm1[r]);
    float w2 = expf(le2[i] - lm2[r]);
    unsigned rank = atomicAdd(&lcur[r], 1u);
    unsigned p = lbase[r] + rank;
    meta[p] = make_float4(__int_as_float(h), __int_as_float(t), w1, w2);
  }
}

// ================= K5: per-relation weighted gather-reduce (fp16 gather) ====
#define SPLIT 4
__global__ __launch_bounds__(256) void k5_reduce(
    const unsigned* __restrict__ offs,
    const float4* __restrict__ meta,
    const __half* __restrict__ xhH, const __half* __restrict__ xtH,
    float* __restrict__ accH, float* __restrict__ accT,
    float* __restrict__ S1, float* __restrict__ S2)
{
  const int r    = blockIdx.x >> 2;
  const int sp   = blockIdx.x & 3;
  const int team = threadIdx.x >> 6;
  const int lane = threadIdx.x & 63;
  const unsigned start = offs[r], end = offs[r + 1];
  const unsigned len = end - start;
  const int ci = sp * 4 + team;
  unsigned b0 = start + (unsigned)(((unsigned long long)len * ci) >> 4);
  unsigned b1 = start + (unsigned)(((unsigned long long)len * (ci + 1)) >> 4);
  const int d0 = lane * 2;

  float a1x = 0.f, a1y = 0.f, a2x = 0.f, a2y = 0.f, sw1 = 0.f, sw2 = 0.f;
  unsigned p = b0;
  for (; p + 4 <= b1; p += 4) {
    float4 md[4];
    #pragma unroll
    for (int u = 0; u < 4; ++u) md[u] = meta[p + u];
    #pragma unroll
    for (int u = 0; u < 4; ++u) {
      const int h = __float_as_int(md[u].x);
      const int t = __float_as_int(md[u].y);
      const float w1 = md[u].z, w2 = md[u].w;
      float2 xa = __half22float2(*(const __half2*)(xhH + (size_t)h * R_HID + d0));
      float2 xb = __half22float2(*(const __half2*)(xtH + (size_t)t * R_HID + d0));
      a1x += w1 * xa.x; a1y += w1 * xa.y;
      a2x += w2 * xb.x; a2y += w2 * xb.y;
      sw1 += w1; sw2 += w2;
    }
  }
  for (; p < b1; ++p) {
    float4 md = meta[p];
    const int h = __float_as_int(md.x);
    const int t = __float_as_int(md.y);
    const float w1 = md.z, w2 = md.w;
    float2 xa = __half22float2(*(const __half2*)(xhH + (size_t)h * R_HID + d0));
    float2 xb = __half22float2(*(const __half2*)(xtH + (size_t)t * R_HID + d0));
    a1x += w1 * xa.x; a1y += w1 * xa.y;
    a2x += w2 * xb.x; a2y += w2 * xb.y;
    sw1 += w1; sw2 += w2;
  }
  atomicAdd(accH + (size_t)r * R_HID + d0,     a1x);
  atomicAdd(accH + (size_t)r * R_HID + d0 + 1, a1y);
  atomicAdd(accT + (size_t)r * R_HID + d0,     a2x);
  atomicAdd(accT + (size_t)r * R_HID + d0 + 1, a2y);
  if (lane == 0) { atomicAdd(S1 + r, sw1); atomicAdd(S2 + r, sw2); }
}

// ================= K6: finalize =============================================
__global__ __launch_bounds__(256) void k6_final(
    const float* __restrict__ accH, const float* __restrict__ accT,
    const float* __restrict__ S1, const float* __restrict__ S2,
    float* __restrict__ out)
{
  int i = blockIdx.x * 256 + threadIdx.x;
  if (i >= NREL * R_HID) return;
  int r = i >> 7;
  out[i] = accH[i] / (S1[r] + EPSF) + accT[i] / (S2[r] + EPSF);
}

extern "C" void kernel_launch(void* const* d_in, const int* in_sizes, int n_in,
                              void* d_out, int out_size, void* d_ws, size_t ws_size,
                              hipStream_t stream) {
  const float* xe  = (const float*)d_in[0];
  const int*   ei  = (const int*)d_in[1];
  const int*   rel = (const int*)d_in[2];
  const float* Wh  = (const float*)d_in[3];
  const float* Wt  = (const float*)d_in[4];
  const float* ah1 = (const float*)d_in[5];
  const float* ah2 = (const float*)d_in[6];
  const float* at1 = (const float*)d_in[7];
  const float* at2 = (const float*)d_in[8];
  const int N = in_sizes[0] / E_HID;
  const int E = in_sizes[2];

  char* w = (char*)d_ws;
  size_t o = 0;
  auto alloc = [&](size_t bytes) -> void* {
    void* p = w + o;
    o = (o + bytes + 255) & ~(size_t)255;
    return p;
  };
  __half* xhH = (__half*)alloc((size_t)N * R_HID * 2);
  __half* xtH = (__half*)alloc((size_t)N * R_HID * 2);
  float* sh1 = (float*)alloc((size_t)N * 4);
  float* sh2 = (float*)alloc((size_t)N * 4);
  float* st1 = (float*)alloc((size_t)N * 4);
  float* st2 = (float*)alloc((size_t)N * 4);
  float* le1 = (float*)alloc((size_t)E * 4);
  float* le2 = (float*)alloc((size_t)E * 4);
  float4* meta = (float4*)alloc((size_t)E * 16);
  unsigned* blockCnt = (unsigned*)alloc((size_t)NB * NREL * 4);
  unsigned* pre      = (unsigned*)alloc((size_t)NB * NREL * 4);
  unsigned* cnt      = (unsigned*)alloc((size_t)NREL * 4);
  unsigned* offs     = (unsigned*)alloc((size_t)(NREL + 1) * 4);
  float* m1f = (float*)alloc((size_t)NREL * 4);
  float* m2f = (float*)alloc((size_t)NREL * 4);
  const size_t zstart = o;  // zero-init region starts here
  unsigned* m1u = (unsigned*)alloc((size_t)NREL * 4);
  unsigned* m2u = (unsigned*)alloc((size_t)NREL * 4);
  float* S1  = (float*)alloc((size_t)NREL * 4);
  float* S2  = (float*)alloc((size_t)NREL * 4);
  float* accH = (float*)alloc((size_t)NREL * R_HID * 4);
  float* accT = (float*)alloc((size_t)NREL * R_HID * 4);
  const size_t zbytes = o - zstart;

  hipMemsetAsync(w + zstart, 0, zbytes, stream);

  k1_gemm<<<(N + 63) / 64, 256, 0, stream>>>(xe, Wh, Wt, ah1, ah2, at1, at2,
                                             xhH, xtH, sh1, sh2, st1, st2, N);
  k2_edge<<<NB, 256, 0, stream>>>(ei, rel, sh1, sh2, st1, st2,
                                  le1, le2, m1u, m2u, blockCnt, E);
  k3a_scan<<<NREL, 64, 0, stream>>>(blockCnt, pre, cnt);
  k3b_scan<<<1, 1024, 0, stream>>>(cnt, offs, m1u, m2u, m1f, m2f);
  k4_scatter<<<NB, 256, 0, stream>>>(ei, rel, le1, le2, m1f, m2f,
                                     offs, pre, meta, E);
  k5_reduce<<<NREL * SPLIT, 256, 0, stream>>>(offs, meta, xhH, xtH,
                                              accH, accT, S1, S2);
  k6_final<<<(NREL * R_HID + 255) / 256, 256, 0, stream>>>(accH, accT, S1, S2,
                                                           (float*)d_out);
}

// Round 3
// 264.181 us; speedup vs baseline: 3.8366x; 1.2189x over previous
//
#include <hip/hip_runtime.h>
#include <hip/hip_fp16.h>
#include <cstdint>
#include <cstddef>

#define E_HID 256
#define R_HID 128
#define NREL  1000
#define EPSF  1e-16f
#define NB    512   // grid-stride blocks for edge passes (k2/k4)
#define SPLIT 4

typedef _Float16 f16x8 __attribute__((ext_vector_type(8)));
typedef float f32x4 __attribute__((ext_vector_type(4)));

struct alignas(16) h8 { __half2 a, b, c, d; };
struct alignas(8)  h4s { __half2 a, b; };

// ================= K0: WcT[c][k] = fp16 of (c<128 ? Wh[k][c] : Wt[k][c-128])
__global__ __launch_bounds__(256) void k0_prep(
    const float* __restrict__ Wh, const float* __restrict__ Wt,
    __half* __restrict__ WcT)
{
  const int k = blockIdx.x;      // 0..255
  const int c = threadIdx.x;     // 0..255
  const float v = (c < R_HID) ? Wh[(size_t)k * R_HID + c]
                              : Wt[(size_t)k * R_HID + (c - R_HID)];
  WcT[(size_t)c * E_HID + k] = __float2half(v);
}

// ================= K1: MFMA fp16 GEMM: [x_r_h | x_r_t] = x_e @ [Wh|Wt]
// grid = nbm*2 (col-block cb: 0->Wh product, 1->Wt product); block = 4 waves
// block tile 128 nodes x 128 cols; wave tile 64x64 (4x4 of 16x16x32 MFMA)
// Fused: per-node fp32 scores (cb0: sh1,st1; cb1: sh2,st2)
__global__ __launch_bounds__(256) void k1_gemm(
    const float* __restrict__ xe, const __half* __restrict__ WcT,
    const float* __restrict__ ah1, const float* __restrict__ ah2,
    const float* __restrict__ at1, const float* __restrict__ at2,
    __half* __restrict__ xhH, __half* __restrict__ xtH,
    float* __restrict__ sh1, float* __restrict__ sh2,
    float* __restrict__ st1, float* __restrict__ st2, int N)
{
  __shared__ __half As[128 * 32];
  __shared__ __half Bs[128 * 32];
  __shared__ float sA[2][128];
  __shared__ float sB[2][128];

  const int tid  = threadIdx.x;
  const int lane = tid & 63;
  const int wid  = tid >> 6;
  const int wr = wid >> 1, wc = wid & 1;
  const int nbm = (N + 127) >> 7;
  const int mb = blockIdx.x % nbm;
  const int cb = blockIdx.x / nbm;      // 0 or 1
  const int n0 = mb * 128;

  f32x4 acc[4][4];
  #pragma unroll
  for (int m = 0; m < 4; ++m)
    #pragma unroll
    for (int n = 0; n < 4; ++n) acc[m][n] = (f32x4){0.f, 0.f, 0.f, 0.f};

  const int arow = tid >> 1, ah = tid & 1;
  const bool aok = (n0 + arow) < N;
  const float*  xsrc = xe + (size_t)(n0 + arow) * E_HID + ah * 16;
  const __half* bsrc = WcT + ((size_t)(cb * 128 + arow) << 8) + ah * 16;
  __half* Aw = &As[arow * 32 + ah * 16];
  __half* Bw = &Bs[arow * 32 + ah * 16];

  const int fr = lane & 15, fq = lane >> 4;  // frag row/col, k-quarter

  for (int kt = 0; kt < 8; ++kt) {
    __syncthreads();
    // ---- stage A (fp32 -> fp16) ----
    float4 v0 = make_float4(0,0,0,0), v1 = v0, v2 = v0, v3 = v0;
    if (aok) {
      const float* s = xsrc + kt * 32;
      v0 = *(const float4*)(s);     v1 = *(const float4*)(s + 4);
      v2 = *(const float4*)(s + 8); v3 = *(const float4*)(s + 12);
    }
    h8 p0, p1;
    p0.a = __floats2half2_rn(v0.x, v0.y); p0.b = __floats2half2_rn(v0.z, v0.w);
    p0.c = __floats2half2_rn(v1.x, v1.y); p0.d = __floats2half2_rn(v1.z, v1.w);
    p1.a = __floats2half2_rn(v2.x, v2.y); p1.b = __floats2half2_rn(v2.z, v2.w);
    p1.c = __floats2half2_rn(v3.x, v3.y); p1.d = __floats2half2_rn(v3.z, v3.w);
    *(h8*)(Aw) = p0; *(h8*)(Aw + 8) = p1;
    // ---- stage B (fp16 copy) ----
    float4 b0 = *(const float4*)(bsrc + kt * 32);
    float4 b1 = *(const float4*)(bsrc + kt * 32 + 8);
    *(float4*)(Bw) = b0; *(float4*)(Bw + 8) = b1;
    __syncthreads();
    // ---- frags + MFMA ----
    f16x8 aF[4], bF[4];
    #pragma unroll
    for (int m = 0; m < 4; ++m)
      aF[m] = *(const f16x8*)&As[(wr * 64 + m * 16 + fr) * 32 + fq * 8];
    #pragma unroll
    for (int n = 0; n < 4; ++n)
      bF[n] = *(const f16x8*)&Bs[(wc * 64 + n * 16 + fr) * 32 + fq * 8];
    #pragma unroll
    for (int m = 0; m < 4; ++m)
      #pragma unroll
      for (int n = 0; n < 4; ++n)
        acc[m][n] = __builtin_amdgcn_mfma_f32_16x16x32_f16(aF[m], bF[n], acc[m][n], 0, 0, 0);
  }

  // ---- write x_r tile (fp16) ----
  __half* dst = (cb == 0) ? xhH : xtH;
  #pragma unroll
  for (int m = 0; m < 4; ++m) {
    const int rl0 = wr * 64 + m * 16 + fq * 4;
    #pragma unroll
    for (int r = 0; r < 4; ++r) {
      const int node = n0 + rl0 + r;
      if (node < N) {
        #pragma unroll
        for (int n = 0; n < 4; ++n)
          dst[(size_t)node * R_HID + wc * 64 + n * 16 + fr] = __float2half(acc[m][n][r]);
      }
    }
  }

  // ---- fused per-node scores (exact fp32 from accumulators) ----
  const float* aV1 = (cb == 0) ? ah1 : ah2;
  const float* aV2 = (cb == 0) ? at1 : at2;
  float avA[4], avB[4];
  #pragma unroll
  for (int n = 0; n < 4; ++n) {
    avA[n] = aV1[wc * 64 + n * 16 + fr];
    avB[n] = aV2[wc * 64 + n * 16 + fr];
  }
  #pragma unroll
  for (int m = 0; m < 4; ++m)
    #pragma unroll
    for (int r = 0; r < 4; ++r) {
      float vA = acc[m][0][r]*avA[0] + acc[m][1][r]*avA[1]
               + acc[m][2][r]*avA[2] + acc[m][3][r]*avA[3];
      float vB = acc[m][0][r]*avB[0] + acc[m][1][r]*avB[1]
               + acc[m][2][r]*avB[2] + acc[m][3][r]*avB[3];
      #pragma unroll
      for (int ofs = 1; ofs < 16; ofs <<= 1) {
        vA += __shfl_xor(vA, ofs, 16);
        vB += __shfl_xor(vB, ofs, 16);
      }
      if (fr == 0) {
        const int rl = wr * 64 + m * 16 + fq * 4 + r;
        sA[wc][rl] = vA;
        sB[wc][rl] = vB;
      }
    }
  __syncthreads();
  if (tid < 128 && n0 + tid < N) {
    float* o1 = (cb == 0) ? sh1 : sh2;
    float* o2 = (cb == 0) ? st1 : st2;
    o1[n0 + tid] = sA[0][tid] + sA[1][tid];
    o2[n0 + tid] = sB[0][tid] + sB[1][tid];
  }
}

// ================= K2: rel histogram only (per-block counts) ================
__global__ __launch_bounds__(256) void k2_hist(
    const int* __restrict__ rel, unsigned* __restrict__ blockCnt, int E)
{
  __shared__ unsigned lcnt[NREL];
  const int tid = threadIdx.x;
  for (int j = tid; j < NREL; j += 256) lcnt[j] = 0u;
  __syncthreads();
  for (int i = blockIdx.x * 256 + tid; i < E; i += NB * 256)
    atomicAdd(&lcnt[rel[i]], 1u);
  __syncthreads();
  for (int j = tid; j < NREL; j += 256)
    blockCnt[(size_t)blockIdx.x * NREL + j] = lcnt[j];
}

// ================= K3a: per-relation exclusive scan over block counts =======
__global__ __launch_bounds__(64) void k3a_scan(
    const unsigned* __restrict__ blockCnt, unsigned* __restrict__ pre,
    unsigned* __restrict__ cnt)
{
  const int r = blockIdx.x;
  const int lane = threadIdx.x;
  unsigned running = 0u;
  for (int b0 = 0; b0 < NB; b0 += 64) {
    const int b = b0 + lane;
    unsigned v = blockCnt[(size_t)b * NREL + r];
    unsigned inc = v;
    #pragma unroll
    for (int ofs = 1; ofs < 64; ofs <<= 1) {
      unsigned nv = __shfl_up(inc, ofs, 64);
      if (lane >= ofs) inc += nv;
    }
    pre[(size_t)b * NREL + r] = running + inc - v;
    running += __shfl(inc, 63, 64);
  }
  if (lane == 0) cnt[r] = running;
}

// ================= K3b: scan totals -> offs ================================
__global__ __launch_bounds__(1024) void k3b_scan(
    const unsigned* __restrict__ cnt, unsigned* __restrict__ offs)
{
  __shared__ unsigned s[1024];
  const int t = threadIdx.x;
  s[t] = (t < NREL) ? cnt[t] : 0u;
  __syncthreads();
  for (int ofs = 1; ofs < 1024; ofs <<= 1) {
    unsigned add = (t >= ofs) ? s[t - ofs] : 0u;
    __syncthreads();
    s[t] += add;
    __syncthreads();
  }
  if (t == 0) offs[0] = 0u;
  if (t < NREL) offs[t + 1] = s[t];
}

// ================= K4: counting-sort scatter, w = exp(l) (no max pass) ======
__global__ __launch_bounds__(256) void k4_scatter(
    const int* __restrict__ ei, const int* __restrict__ rel,
    const float* __restrict__ sh1, const float* __restrict__ sh2,
    const float* __restrict__ st1, const float* __restrict__ st2,
    const unsigned* __restrict__ offs, const unsigned* __restrict__ pre,
    float4* __restrict__ meta, int E)
{
  __shared__ unsigned lcur[NREL];
  __shared__ unsigned lbase[NREL];
  const int tid = threadIdx.x;
  for (int j = tid; j < NREL; j += 256) {
    lcur[j] = 0u;
    lbase[j] = offs[j] + pre[(size_t)blockIdx.x * NREL + j];
  }
  __syncthreads();
  for (int i = blockIdx.x * 256 + tid; i < E; i += NB * 256) {
    int h = ei[i], t = ei[E + i], r = rel[i];
    float e1 = sh1[h] + sh2[t];
    float e2 = st1[h] + st2[t];
    float l1 = e1 >= 0.f ? e1 : 0.01f * e1;
    float l2 = e2 >= 0.f ? e2 : 0.01f * e2;
    float w1 = expf(l1);
    float w2 = expf(l2);
    unsigned rank = atomicAdd(&lcur[r], 1u);
    unsigned p = lbase[r] + rank;
    meta[p] = make_float4(__int_as_float(h), __int_as_float(t), w1, w2);
  }
}

// ================= K5: per-relation weighted gather-reduce (fp16, 2 edges/wave)
__global__ __launch_bounds__(256) void k5_reduce(
    const unsigned* __restrict__ offs,
    const float4* __restrict__ meta,
    const __half* __restrict__ xhH, const __half* __restrict__ xtH,
    float* __restrict__ accH, float* __restrict__ accT,
    float* __restrict__ S1, float* __restrict__ S2)
{
  const int r    = blockIdx.x >> 2;
  const int sp   = blockIdx.x & 3;
  const int team = threadIdx.x >> 6;
  const int lane = threadIdx.x & 63;
  const int es   = lane >> 5;        // edge slot 0/1
  const int dl   = lane & 31;        // dim lane
  const int d0   = dl * 4;           // 4 dims (8B fp16) per lane
  const unsigned start = offs[r], end = offs[r + 1];
  const unsigned len = end - start;
  const int ci = sp * 4 + team;      // 0..15 chunks per relation
  const unsigned b0 = start + (unsigned)(((unsigned long long)len * ci) >> 4);
  const unsigned b1 = start + (unsigned)(((unsigned long long)len * (ci + 1)) >> 4);

  float a1[4] = {0.f, 0.f, 0.f, 0.f};
  float a2[4] = {0.f, 0.f, 0.f, 0.f};
  float sw1 = 0.f, sw2 = 0.f;

  for (unsigned base = b0; base < b1; base += 8) {
    #pragma unroll
    for (int u = 0; u < 4; ++u) {
      const unsigned idx = base + 2u * u + (unsigned)es;
      if (idx < b1) {
        const float4 md = meta[idx];
        const int h = __float_as_int(md.x);
        const int t = __float_as_int(md.y);
        const float w1 = md.z, w2 = md.w;
        h4s va = *(const h4s*)(xhH + (size_t)h * R_HID + d0);
        h4s vb = *(const h4s*)(xtH + (size_t)t * R_HID + d0);
        float2 fa0 = __half22float2(va.a), fa1 = __half22float2(va.b);
        float2 fb0 = __half22float2(vb.a), fb1 = __half22float2(vb.b);
        a1[0] += w1 * fa0.x; a1[1] += w1 * fa0.y;
        a1[2] += w1 * fa1.x; a1[3] += w1 * fa1.y;
        a2[0] += w2 * fb0.x; a2[1] += w2 * fb0.y;
        a2[2] += w2 * fb1.x; a2[3] += w2 * fb1.y;
        sw1 += w1; sw2 += w2;
      }
    }
  }
  // combine the two edge-slot halves (lane <-> lane^32 hold same dims)
  #pragma unroll
  for (int j = 0; j < 4; ++j) {
    a1[j] += __shfl_xor(a1[j], 32);
    a2[j] += __shfl_xor(a2[j], 32);
  }
  sw1 += __shfl_xor(sw1, 32);
  sw2 += __shfl_xor(sw2, 32);
  if (lane < 32) {
    #pragma unroll
    for (int j = 0; j < 4; ++j) {
      atomicAdd(accH + (size_t)r * R_HID + d0 + j, a1[j]);
      atomicAdd(accT + (size_t)r * R_HID + d0 + j, a2[j]);
    }
    if (lane == 0) { atomicAdd(S1 + r, sw1); atomicAdd(S2 + r, sw2); }
  }
}

// ================= K6: finalize =============================================
__global__ __launch_bounds__(256) void k6_final(
    const float* __restrict__ accH, const float* __restrict__ accT,
    const float* __restrict__ S1, const float* __restrict__ S2,
    float* __restrict__ out)
{
  int i = blockIdx.x * 256 + threadIdx.x;
  if (i >= NREL * R_HID) return;
  int r = i >> 7;
  out[i] = accH[i] / (S1[r] + EPSF) + accT[i] / (S2[r] + EPSF);
}

extern "C" void kernel_launch(void* const* d_in, const int* in_sizes, int n_in,
                              void* d_out, int out_size, void* d_ws, size_t ws_size,
                              hipStream_t stream) {
  const float* xe  = (const float*)d_in[0];
  const int*   ei  = (const int*)d_in[1];
  const int*   rel = (const int*)d_in[2];
  const float* Wh  = (const float*)d_in[3];
  const float* Wt  = (const float*)d_in[4];
  const float* ah1 = (const float*)d_in[5];
  const float* ah2 = (const float*)d_in[6];
  const float* at1 = (const float*)d_in[7];
  const float* at2 = (const float*)d_in[8];
  const int N = in_sizes[0] / E_HID;
  const int E = in_sizes[2];

  char* w = (char*)d_ws;
  size_t o = 0;
  auto alloc = [&](size_t bytes) -> void* {
    void* p = w + o;
    o = (o + bytes + 255) & ~(size_t)255;
    return p;
  };
  __half* WcT = (__half*)alloc((size_t)E_HID * E_HID * 2);
  __half* xhH = (__half*)alloc((size_t)N * R_HID * 2);
  __half* xtH = (__half*)alloc((size_t)N * R_HID * 2);
  float* sh1 = (float*)alloc((size_t)N * 4);
  float* sh2 = (float*)alloc((size_t)N * 4);
  float* st1 = (float*)alloc((size_t)N * 4);
  float* st2 = (float*)alloc((size_t)N * 4);
  float4* meta = (float4*)alloc((size_t)E * 16);
  unsigned* blockCnt = (unsigned*)alloc((size_t)NB * NREL * 4);
  unsigned* pre      = (unsigned*)alloc((size_t)NB * NREL * 4);
  unsigned* cnt      = (unsigned*)alloc((size_t)NREL * 4);
  unsigned* offs     = (unsigned*)alloc((size_t)(NREL + 1) * 4);
  const size_t zstart = o;  // zero-init region starts here
  float* S1  = (float*)alloc((size_t)NREL * 4);
  float* S2  = (float*)alloc((size_t)NREL * 4);
  float* accH = (float*)alloc((size_t)NREL * R_HID * 4);
  float* accT = (float*)alloc((size_t)NREL * R_HID * 4);
  const size_t zbytes = o - zstart;

  hipMemsetAsync(w + zstart, 0, zbytes, stream);

  const int nbm = (N + 127) >> 7;
  k0_prep<<<E_HID, 256, 0, stream>>>(Wh, Wt, WcT);
  k1_gemm<<<nbm * 2, 256, 0, stream>>>(xe, WcT, ah1, ah2, at1, at2,
                                       xhH, xtH, sh1, sh2, st1, st2, N);
  k2_hist<<<NB, 256, 0, stream>>>(rel, blockCnt, E);
  k3a_scan<<<NREL, 64, 0, stream>>>(blockCnt, pre, cnt);
  k3b_scan<<<1, 1024, 0, stream>>>(cnt, offs);
  k4_scatter<<<NB, 256, 0, stream>>>(ei, rel, sh1, sh2, st1, st2,
                                     offs, pre, meta, E);
  k5_reduce<<<NREL * SPLIT, 256, 0, stream>>>(offs, meta, xhH, xtH,
                                              accH, accT, S1, S2);
  k6_final<<<(NREL * R_HID + 255) / 256, 256, 0, stream>>>(accH, accT, S1, S2,
                                                           (float*)d_out);
}